// Round 6
// baseline (1357.071 us; speedup 1.0000x reference)
//
#include <hip/hip_runtime.h>
#include <hip/hip_bf16.h>

#define N_NODES 16384
#define E_EDGES 262144
#define IN_DIM 512

// fixed-point scale for deterministic aggregation
#define AGG_SCALE 1099511627776.0   // 2^40
#define AGG_INV   (1.0/1099511627776.0)

// ---------------- edge dtype detection + access ----------------
__global__ void detect_kernel(const void* __restrict__ ei, unsigned* __restrict__ diag) {
    const unsigned long long v = ((const unsigned long long*)ei)[threadIdx.x];
    const int small = (v < 16384ull) ? 1 : 0;
    const int all64 = __all(small);
    if (threadIdx.x == 0) diag[0] = all64 ? 1u : 0u;
}

__device__ __forceinline__ int edge_at(const void* __restrict__ ei, int is64, int pos) {
    return is64 ? (int)(((const long long*)ei)[pos]) : ((const int*)ei)[pos];
}

// ---------------- degree ----------------
__global__ __launch_bounds__(256) void deg_kernel(const void* __restrict__ ei,
                                                  const unsigned* __restrict__ diag,
                                                  int* __restrict__ deg) {
    const int is64 = (int)diag[0];
    int e = blockIdx.x * 256 + threadIdx.x;
    int r = edge_at(ei, is64, e);
    if (r >= 0 && r < N_NODES) atomicAdd(&deg[r], 1);
}

// dinv in f32, correctly rounded sqrt+div (matches 1.0/np.sqrt(deg) bit-exactly)
__global__ __launch_bounds__(256) void dinv_kernel(const int* __restrict__ deg, float* __restrict__ dinv) {
    int i = blockIdx.x * 256 + threadIdx.x;
    int d = deg[i];
    dinv[i] = (d > 0) ? __fdiv_rn(1.0f, __fsqrt_rn((float)d)) : 0.0f;
}

// ---------------- MLP: f32, k-ascending single-accumulator fmaf chains ----------------
// Matches BLAS sgemm per-element accumulation (vectorized over outputs, sequential in k).
__device__ __forceinline__ void dense_layer32(float (*hsw)[64], int c,
                                              const float* __restrict__ WP,
                                              const float* __restrict__ BP,
                                              bool relu, bool last,
                                              float* __restrict__ gout, int n0)
{
    float s0 = 0.0f, s1 = 0.0f, s2 = 0.0f, s3 = 0.0f;
    #pragma unroll 1
    for (int k = 0; k < 64; ++k) {
        const float wv = WP[k * 64 + c];
        s0 = fmaf(hsw[0][k], wv, s0);
        s1 = fmaf(hsw[1][k], wv, s1);
        s2 = fmaf(hsw[2][k], wv, s2);
        s3 = fmaf(hsw[3][k], wv, s3);
    }
    const float bv = BP[c];
    s0 += bv; s1 += bv; s2 += bv; s3 += bv;    // separate rounded add, like np matmul + bias
    if (relu) { s0 = fmaxf(s0, 0.0f); s1 = fmaxf(s1, 0.0f); s2 = fmaxf(s2, 0.0f); s3 = fmaxf(s3, 0.0f); }
    __syncthreads();
    if (last) {
        gout[(size_t)(n0 + 0) * 64 + c] = s0;
        gout[(size_t)(n0 + 1) * 64 + c] = s1;
        gout[(size_t)(n0 + 2) * 64 + c] = s2;
        gout[(size_t)(n0 + 3) * 64 + c] = s3;
    } else {
        hsw[0][c] = s0; hsw[1][c] = s1; hsw[2][c] = s2; hsw[3][c] = s3;
    }
    __syncthreads();
}

__global__ __launch_bounds__(256) void mlp_kernel(
    const float* __restrict__ x,
    const float* __restrict__ W1, const float* __restrict__ b1,
    const float* __restrict__ W2, const float* __restrict__ b2,
    const float* __restrict__ W3, const float* __restrict__ b3,
    const float* __restrict__ W4, const float* __restrict__ b4,
    const float* __restrict__ Wg1, const float* __restrict__ bg1,
    const float* __restrict__ Wg2, const float* __restrict__ bg2,
    float* __restrict__ g32)
{
    __shared__ float hs[4][4][64];
    const int w = threadIdx.x >> 6;
    const int c = threadIdx.x & 63;
    const int n0 = blockIdx.x * 16 + w * 4;

    float a0 = 0.0f, a1 = 0.0f, a2 = 0.0f, a3 = 0.0f;
    const float* xp = x + (size_t)n0 * IN_DIM;
    #pragma unroll 1
    for (int k = 0; k < IN_DIM; ++k) {
        const float wv = W1[k * 64 + c];
        a0 = fmaf(xp[k],              wv, a0);
        a1 = fmaf(xp[IN_DIM + k],     wv, a1);
        a2 = fmaf(xp[2 * IN_DIM + k], wv, a2);
        a3 = fmaf(xp[3 * IN_DIM + k], wv, a3);
    }
    const float bv = b1[c];
    hs[w][0][c] = fmaxf(a0 + bv, 0.0f);
    hs[w][1][c] = fmaxf(a1 + bv, 0.0f);
    hs[w][2][c] = fmaxf(a2 + bv, 0.0f);
    hs[w][3][c] = fmaxf(a3 + bv, 0.0f);
    __syncthreads();

    dense_layer32(hs[w], c, W2, b2, false, false, g32, n0);
    dense_layer32(hs[w], c, W3, b3, true,  false, g32, n0);
    dense_layer32(hs[w], c, W4, b4, false, false, g32, n0);
    dense_layer32(hs[w], c, Wg1, bg1, true, false, g32, n0);
    dense_layer32(hs[w], c, Wg2, bg2, false, true, g32, n0);
}

// ---------------- aggregation: f32 msg terms, int64 fixed-point atomics ----------------
__global__ __launch_bounds__(256) void agg_kernel(
    const void* __restrict__ ei, const unsigned* __restrict__ diag,
    const float* __restrict__ dinv, const float* __restrict__ g32,
    unsigned long long* __restrict__ aggq)
{
    const int is64 = (int)diag[0];
    int t = blockIdx.x * 256 + threadIdx.x;
    int e = t >> 6, h = t & 63;
    int r  = edge_at(ei, is64, e);
    int cc = edge_at(ei, is64, E_EDGES + e);
    if (r < 0 || r >= N_NODES || cc < 0 || cc >= N_NODES) return;
    float tnorm = __fmul_rn(dinv[r], dinv[cc]);                 // (dinv[row]*dinv[col]) rounded
    float m = __fmul_rn(tnorm, g32[(size_t)cc * 64 + h]);       // * g[col] rounded
    long long q = __double2ll_rn((double)m * AGG_SCALE);        // exact quantization of f32 value
    atomicAdd(&aggq[(size_t)r * 64 + h], (unsigned long long)q);
}

// ---------------- finalize: F32 = g32 - agg32 ----------------
__global__ __launch_bounds__(256) void fin_kernel(
    const unsigned long long* __restrict__ aggq,
    const float* __restrict__ g32, float* __restrict__ F32)
{
    int i = blockIdx.x * 256 + threadIdx.x;
    float a = (float)((double)(long long)aggq[i] * AGG_INV);
    F32[i] = g32[i] - a;
}

// ---------------- fused sim GEMM + per-slice top-8 screening ----------------
// Each acc element is a k-ascending single-accumulator fmaf chain == BLAS sgemm rounding.
// grid = 512: (128 row-blocks x 4 col-splits of 4096). 8x8 register tiles, stride-68 LDS.
__global__ __launch_bounds__(256) void simtopk_kernel(
    const float* __restrict__ F, float* __restrict__ candv, int* __restrict__ candi)
{
    __shared__ float Cs[128 * 68];

    const int tid = threadIdx.x;
    const int rb = blockIdx.x >> 2;
    const int q  = blockIdx.x & 3;
    const int r0 = rb * 128;
    const int cbase = q * 4096;
    const int ty = tid >> 4;
    const int tx = tid & 15;

    const int srow = tid >> 1;
    const int scol0 = (tid & 1) * 32;

    float tv[8];
    int tix[8];
    #pragma unroll
    for (int z = 0; z < 8; ++z) { tv[z] = -3.0e38f; tix[z] = 0; }

    const float* Abase = F + (size_t)(r0 + 8 * ty) * 64;

    #pragma unroll 1
    for (int t = 0; t < 32; ++t) {
        const int c0 = cbase + t * 128;
        __syncthreads();
        #pragma unroll
        for (int j = 0; j < 8; ++j) {
            int f = tid + 256 * j;
            int colk = f >> 4;
            int kq = f & 15;
            float4 v = *(const float4*)(F + ((size_t)(c0 + colk) << 6) + (kq << 2));
            *(float4*)(&Cs[colk * 68 + (kq << 2)]) = v;
        }
        __syncthreads();

        float acc[8][8];
        #pragma unroll
        for (int i = 0; i < 8; ++i)
            #pragma unroll
            for (int j = 0; j < 8; ++j) acc[i][j] = 0.0f;

        #pragma unroll 1
        for (int cc = 0; cc < 16; ++cc) {
            float4 av[8];
            #pragma unroll
            for (int i = 0; i < 8; ++i)
                av[i] = *(const float4*)(Abase + (i << 6) + (cc << 2));
            #pragma unroll
            for (int j = 0; j < 8; ++j) {
                const float4 cv = *(const float4*)(&Cs[(tx + 16 * j) * 68 + (cc << 2)]);
                #pragma unroll
                for (int i = 0; i < 8; ++i) {
                    acc[i][j] = fmaf(av[i].x, cv.x, acc[i][j]);
                    acc[i][j] = fmaf(av[i].y, cv.y, acc[i][j]);
                    acc[i][j] = fmaf(av[i].z, cv.z, acc[i][j]);
                    acc[i][j] = fmaf(av[i].w, cv.w, acc[i][j]);
                }
            }
        }

        #pragma unroll 1
        for (int hh = 0; hh < 2; ++hh) {
            __syncthreads();
            #pragma unroll
            for (int jj = 0; jj < 4; ++jj) {
                const int lcol = tx + 16 * jj;
                #pragma unroll
                for (int i = 0; i < 8; ++i)
                    Cs[(8 * ty + i) * 68 + lcol] = acc[i][jj + 4 * hh];
            }
            __syncthreads();
            const int gc = c0 + hh * 64 + scol0;
            const float* srcp = &Cs[srow * 68 + scol0];
            #pragma unroll 1
            for (int u = 0; u < 8; ++u) {
                float4 v = *(const float4*)(srcp + 4 * u);
                const int gi = gc + 4 * u;
                #pragma unroll
                for (int comp = 0; comp < 4; ++comp) {
                    float vv = comp == 0 ? v.x : comp == 1 ? v.y : comp == 2 ? v.z : v.w;
                    if (vv > tv[7]) {          // strict: earlier (lower) index kept on ties
                        tv[7] = vv; tix[7] = gi + comp;
                        #pragma unroll
                        for (int z = 7; z >= 1; --z) {
                            if (tv[z] > tv[z - 1]) {
                                float tf = tv[z]; tv[z] = tv[z - 1]; tv[z - 1] = tf;
                                int ti = tix[z]; tix[z] = tix[z - 1]; tix[z - 1] = ti;
                            }
                        }
                    }
                }
            }
        }
    }

    const int grow = r0 + (tid >> 1);
    const size_t base = ((size_t)q * N_NODES + grow) * 16 + (tid & 1) * 8;
    #pragma unroll
    for (int z = 0; z < 8; ++z) { candv[base + z] = tv[z]; candi[base + z] = tix[z]; }
}

// ---------------- refine: exact merge of 64 (val,idx) pairs -> stable top-8 ----------------
// Candidates provably contain the true top-8 (per-subset top-8 of exact chain values).
__global__ __launch_bounds__(256) void refine_kernel(
    const float* __restrict__ candv, const int* __restrict__ candi,
    float* __restrict__ resv, int* __restrict__ residx)
{
    const int w = threadIdx.x >> 6;
    const int lane = threadIdx.x & 63;
    const int row = blockIdx.x * 4 + w;

    const size_t cbase = ((size_t)(lane >> 4) * N_NODES + row) * 16 + (lane & 15);
    float v = candv[cbase];
    int  ci = candi[cbase];

    #pragma unroll 1
    for (int it = 0; it < 8; ++it) {
        float bv = v; int bi = ci;
        #pragma unroll
        for (int off = 32; off > 0; off >>= 1) {
            float ov = __shfl_xor(bv, off);
            int   oi = __shfl_xor(bi, off);
            if (ov > bv || (ov == bv && oi < bi)) { bv = ov; bi = oi; }
        }
        if (lane == 0) {
            resv[(size_t)row * 8 + it] = bv;
            residx[(size_t)row * 8 + it] = bi;
        }
        if (ci == bi) v = -3.4e38f;   // remove winner (indices are distinct per row)
    }
}

// ---------------- emit: FLOAT32 outputs ----------------
__global__ __launch_bounds__(256) void emit_kernel(
    const float* __restrict__ resv, const int* __restrict__ residx,
    float* __restrict__ out)
{
    const int j = blockIdx.x * 256 + threadIdx.x;
    if (j < 131072) {
        out[j] = resv[j];                             // topk_vals
    } else if (j < 262144) {
        out[j] = (float)((j - 131072) >> 3);          // new_edge_index row 0: src = slot/8
    } else {
        out[j] = (float)residx[j - 262144];           // new_edge_index row 1: topk_idx
    }
}

__global__ void canary_kernel(float* out, float code) {
    out[0] = code;
}

// ---------------- launch ----------------
extern "C" void kernel_launch(void* const* d_in, const int* in_sizes, int n_in,
                              void* d_out, int out_size, void* d_ws, size_t ws_size,
                              hipStream_t stream)
{
    const float* x   = (const float*)d_in[0];
    const void*  ei  = d_in[1];
    const float* W1  = (const float*)d_in[2];  const float* b1  = (const float*)d_in[3];
    const float* W2  = (const float*)d_in[4];  const float* b2  = (const float*)d_in[5];
    const float* W3  = (const float*)d_in[6];  const float* b3  = (const float*)d_in[7];
    const float* W4  = (const float*)d_in[8];  const float* b4  = (const float*)d_in[9];
    const float* Wg1 = (const float*)d_in[10]; const float* bg1 = (const float*)d_in[11];
    const float* Wg2 = (const float*)d_in[12]; const float* bg2 = (const float*)d_in[13];
    float* out = (float*)d_out;

    // workspace layout
    char* ws = (char*)d_ws;
    float* g32 = (float*)(ws);                                       // [0, 4M)
    float* F32 = (float*)(ws + ((size_t)4 << 20));                   // [4M, 8M)
    unsigned long long* aggq = (unsigned long long*)(ws + ((size_t)8 << 20)); // [8M, 16M)
    float* resv = (float*)(ws + ((size_t)8 << 20));                  // 512KB, overlays aggq (dead after fin)
    int* residx = (int*)(ws + ((size_t)8 << 20) + ((size_t)1 << 19));// 512KB
    float* candv = (float*)(ws + ((size_t)16 << 20));                // [16M, 20M)
    int*   candi = (int*)(ws + ((size_t)20 << 20));                  // [20M, 24M)
    int*   deg   = (int*)(ws + ((size_t)24 << 20));                  // 64 KB
    float* dinvf = (float*)(ws + ((size_t)24 << 20) + (1u << 16));   // 64 KB
    unsigned* diag = (unsigned*)(ws + ((size_t)24 << 20) + (2u << 16)); // 256 B

    const size_t NEEDED = ((size_t)24 << 20) + (2u << 16) + 256;
    if (ws_size < NEEDED || n_in < 14) {
        canary_kernel<<<1, 1, 0, stream>>>(out, ws_size < NEEDED ? 5000.0f : 3000.0f);
        return;
    }

    hipMemsetAsync(deg, 0, N_NODES * sizeof(int), stream);
    hipMemsetAsync(aggq, 0, (size_t)N_NODES * 64 * sizeof(unsigned long long), stream);

    detect_kernel<<<1, 64, 0, stream>>>(ei, diag);
    deg_kernel<<<E_EDGES / 256, 256, 0, stream>>>(ei, diag, deg);
    dinv_kernel<<<N_NODES / 256, 256, 0, stream>>>(deg, dinvf);
    mlp_kernel<<<N_NODES / 16, 256, 0, stream>>>(x, W1, b1, W2, b2, W3, b3, W4, b4, Wg1, bg1, Wg2, bg2, g32);
    agg_kernel<<<(E_EDGES * 64) / 256, 256, 0, stream>>>(ei, diag, dinvf, g32, aggq);
    fin_kernel<<<(N_NODES * 64) / 256, 256, 0, stream>>>(aggq, g32, F32);
    simtopk_kernel<<<512, 256, 0, stream>>>(F32, candv, candi);
    refine_kernel<<<N_NODES / 4, 256, 0, stream>>>(candv, candi, resv, residx);
    emit_kernel<<<(N_NODES * 24) / 256, 256, 0, stream>>>(resv, residx, out);
}